// Round 16
// baseline (70.116 us; speedup 1.0000x reference)
//
#include <hip/hip_runtime.h>
#include <hip/hip_cooperative_groups.h>

namespace cg = cooperative_groups;

#define M_HALF 16384
#define D 128
#define C 64
#define NBLK 256
#define KC_ROWS 64

// ---- Phase A: direct prototype build; block owns (class = blk&63, 32-float
//      k-slice = blk>>6). Batched y-scan (16 independent int4 loads/thread),
//      register gather, shuffle reduce, finalized pTg write. ----------------
__device__ __forceinline__ void phase_a(
    const float* __restrict__ x, const int* __restrict__ y,
    float* __restrict__ pTg, float* __restrict__ out, int blk, int tid)
{
    __shared__ float redA[4][32];
    __shared__ int   credw[4];
    const int lane = tid & 63;
    const int wid  = tid >> 6;
    const int myc  = blk & 63;
    const int kq   = blk >> 6;           // 0..3 -> 32-float slice

    if (blk == 0 && tid == 0) out[0] = 0.f;   // before any phase-C atomicAdd

    float acc[32];
    #pragma unroll
    for (int j = 0; j < 32; ++j) acc[j] = 0.f;
    int cnt = 0;

    const float* xb = x + kq * 32;
    const int4* y4 = (const int4*)y;
    #pragma unroll
    for (int half = 0; half < 2; ++half) {
        int4 yv[8];
        #pragma unroll
        for (int i = 0; i < 8; ++i)                  // 8 independent int4 loads
            yv[i] = y4[(half * 8 + i) * 256 + tid];  // coalesced across threads
        #pragma unroll
        for (int i = 0; i < 8; ++i) {
            const int r0 = ((half * 8 + i) * 256 + tid) * 4;
            const int4 v = yv[i];
            #pragma unroll
            for (int s = 0; s < 4; ++s) {
                const int yl = (s == 0) ? v.x : (s == 1) ? v.y : (s == 2) ? v.z : v.w;
                if (yl == myc) {
                    ++cnt;
                    const float4* xr = (const float4*)(xb + (size_t)(r0 + s) * D);
                    #pragma unroll
                    for (int j4 = 0; j4 < 8; ++j4) {
                        const float4 vv = xr[j4];
                        acc[j4*4+0] += vv.x; acc[j4*4+1] += vv.y;
                        acc[j4*4+2] += vv.z; acc[j4*4+3] += vv.w;
                    }
                }
            }
        }
    }

    #pragma unroll
    for (int off = 32; off; off >>= 1) {         // fixed order -> deterministic
        #pragma unroll
        for (int j = 0; j < 32; ++j) acc[j] += __shfl_xor(acc[j], off);
        cnt += __shfl_xor(cnt, off);
    }
    if (lane == 0) {
        #pragma unroll
        for (int j = 0; j < 32; ++j) redA[wid][j] = acc[j];
        credw[wid] = cnt;
    }
    __syncthreads();
    if (tid < 32) {
        float tot = redA[0][tid] + redA[1][tid] + redA[2][tid] + redA[3][tid];
        float c = (float)(credw[0] + credw[1] + credw[2] + credw[3]);
        if (c < 0.5f) c = 1.f;                   // class_counts + (counts<0.01)
        tot /= c;
        const int k = kq * 32 + tid;
        pTg[((k >> 2) * 64 + (myc & 3) * 16 + (myc >> 2)) * 4 + (k & 3)] = tot;
    }
}

// ---- Phase C: 4x4-register-tile distances + logsumexp + atomic loss -------
__device__ __forceinline__ void phase_c(
    const float* __restrict__ x, const int* __restrict__ y,
    const float4* __restrict__ pTg4, float* __restrict__ out, int blk, int tid)
{
    __shared__ float4 pT4[32 * 64];            // 32 KB, [k4][cc][cg]
    __shared__ float  wsum[4];

    for (int o = tid; o < 32 * 64; o += 256) pT4[o] = pTg4[o];
    __syncthreads();

    const int lane = tid & 63;
    const int wid  = tid >> 6;
    const int cg_  = lane & 15;      // classes 4*cg_ + cc
    const int rg   = lane >> 4;      // row group within wave
    const int rbase = wid * 16 + rg * 4;   // wave: 16 rows; thread: 4 rows
    const int row0 = M_HALF + blk * KC_ROWS;

    const float4* xrow[4];
    #pragma unroll
    for (int r = 0; r < 4; ++r)
        xrow[r] = (const float4*)(x + (size_t)(row0 + rbase + r) * D);

    float acc[4][4];
    #pragma unroll
    for (int r = 0; r < 4; ++r)
        #pragma unroll
        for (int cc = 0; cc < 4; ++cc) acc[r][cc] = 0.f;

    float4 xv[4], xvn[4];
    #pragma unroll
    for (int r = 0; r < 4; ++r) xv[r] = xrow[r][0];   // prologue

    #pragma unroll 4
    for (int k4 = 0; k4 < 32; ++k4) {
        if (k4 < 31) {
            #pragma unroll
            for (int r = 0; r < 4; ++r) xvn[r] = xrow[r][k4 + 1];  // prefetch
        }
        float4 pv[4];
        #pragma unroll
        for (int cc = 0; cc < 4; ++cc) pv[cc] = pT4[k4 * 64 + cc * 16 + cg_];
        #pragma unroll
        for (int r = 0; r < 4; ++r) {
            #pragma unroll
            for (int cc = 0; cc < 4; ++cc) {
                float d;
                d = xv[r].x - pv[cc].x; acc[r][cc] = fmaf(d, fabsf(d), acc[r][cc]);
                d = xv[r].y - pv[cc].y; acc[r][cc] = fmaf(d, fabsf(d), acc[r][cc]);
                d = xv[r].z - pv[cc].z; acc[r][cc] = fmaf(d, fabsf(d), acc[r][cc]);
                d = xv[r].w - pv[cc].w; acc[r][cc] = fmaf(d, fabsf(d), acc[r][cc]);
            }
        }
        #pragma unroll
        for (int r = 0; r < 4; ++r) xv[r] = xvn[r];
    }

    const float ninv_d = -1.f / (float)D;
    float lsum = 0.f;
    #pragma unroll
    for (int r = 0; r < 4; ++r) {
        float dv0 = acc[r][0] * ninv_d, dv1 = acc[r][1] * ninv_d;
        float dv2 = acc[r][2] * ninv_d, dv3 = acc[r][3] * ninv_d;
        float mx = fmaxf(fmaxf(dv0, dv1), fmaxf(dv2, dv3));
        #pragma unroll
        for (int off = 8; off; off >>= 1) mx = fmaxf(mx, __shfl_xor(mx, off));
        float se = __expf(dv0 - mx) + __expf(dv1 - mx) +
                   __expf(dv2 - mx) + __expf(dv3 - mx);
        #pragma unroll
        for (int off = 8; off; off >>= 1) se += __shfl_xor(se, off);
        const float lse = mx + __logf(se);

        const int yt  = y[row0 + rbase + r];     // uniform within 16-lane group
        const int cct = yt & 3, cgt = yt >> 2;   // class c = 4*cg + cc
        const float v01 = (cct & 1) ? dv1 : dv0;
        const float v23 = (cct & 1) ? dv3 : dv2;
        const float val = (cct & 2) ? v23 : v01;
        const float dy  = __shfl(val, (lane & 48) | cgt);
        lsum += lse - dy;                        // -logp[y]
    }

    lsum += __shfl_xor(lsum, 16);                // sum 4 rg-groups
    lsum += __shfl_xor(lsum, 32);

    if (lane == 0) wsum[wid] = lsum;
    __syncthreads();
    if (tid == 0) {
        const float tot = (wsum[0] + wsum[1] + wsum[2] + wsum[3]) * (1.f / (float)M_HALF);
        atomicAdd(out, tot);
    }
}

// ---- fused cooperative kernel (1 node) ------------------------------------
__global__ __launch_bounds__(256) void fused_coop(
    const float* __restrict__ x, const int* __restrict__ y,
    float* __restrict__ pTg, float* __restrict__ out)
{
    cg::grid_group grid = cg::this_grid();
    phase_a(x, y, pTg, out, blockIdx.x, threadIdx.x);
    grid.sync();
    phase_c(x, y, (const float4*)pTg, out, blockIdx.x, threadIdx.x);
}

// ---- fallback pair (2 nodes, r15-equivalent) ------------------------------
__global__ __launch_bounds__(256) void kp_fb(
    const float* __restrict__ x, const int* __restrict__ y,
    float* __restrict__ pTg, float* __restrict__ out)
{
    phase_a(x, y, pTg, out, blockIdx.x, threadIdx.x);
}

__global__ __launch_bounds__(256) void kc_fb(
    const float* __restrict__ x, const int* __restrict__ y,
    const float4* __restrict__ pTg4, float* __restrict__ out)
{
    phase_c(x, y, pTg4, out, blockIdx.x, threadIdx.x);
}

extern "C" void kernel_launch(void* const* d_in, const int* in_sizes, int n_in,
                              void* d_out, int out_size, void* d_ws, size_t ws_size,
                              hipStream_t stream) {
    const float* x = (const float*)d_in[0];   // [32768][128]
    const int*   y = (const int*)d_in[1];     // [32768]
    float* out = (float*)d_out;
    float* pTg = (float*)d_ws;                // 8192 floats

    void* args[] = { (void*)&x, (void*)&y, (void*)&pTg, (void*)&out };
    hipError_t err = hipLaunchCooperativeKernel(
        (const void*)fused_coop, dim3(NBLK), dim3(256), args, 0, stream);
    if (err != hipSuccess) {
        // identical math, 2 launches (r15 structure)
        kp_fb<<<NBLK, 256, 0, stream>>>(x, y, pTg, out);
        kc_fb<<<NBLK, 256, 0, stream>>>(x, y, (const float4*)pTg, out);
    }
}

// Round 17
// 35.089 us; speedup vs baseline: 1.9982x; 1.9982x over previous
//
#include <hip/hip_runtime.h>

#define M_HALF 16384
#define D 128
#define C 64

#define KP_BLOCKS 512            // block = (kq8 = blk>>6 in 0..7, class = blk&63)
#define KC_BLOCKS 256
#define KC_ROWS 64

// ---- K_P: direct prototype build (r15, verbatim — validated) --------------
__global__ __launch_bounds__(256) void kp_proto(
    const float* __restrict__ x, const int* __restrict__ y,
    float* __restrict__ pTg,     // float idx: (k4*64 + cc*16 + cg)*4 + j
    float* __restrict__ out)
{
    __shared__ float red[4][16];
    __shared__ int   credw[4];
    const int tid  = threadIdx.x;
    const int lane = tid & 63;
    const int wid  = tid >> 6;
    const int blk  = blockIdx.x;
    const int myc  = blk & 63;
    const int kq8  = blk >> 6;           // 0..7 -> 16-float slice

    if (blk == 0 && tid == 0) out[0] = 0.f;   // before K_C's atomicAdd

    float acc[16];
    #pragma unroll
    for (int j = 0; j < 16; ++j) acc[j] = 0.f;
    int cnt = 0;

    const float* xb = x + kq8 * 16;
    const int4* y4 = (const int4*)y;

    #pragma unroll
    for (int half = 0; half < 2; ++half) {
        int4 yv[8];
        #pragma unroll
        for (int i = 0; i < 8; ++i)                  // 8 independent int4 loads
            yv[i] = y4[(half * 8 + i) * 256 + tid];  // coalesced across threads
        #pragma unroll
        for (int i = 0; i < 8; ++i) {
            const int r0 = ((half * 8 + i) * 256 + tid) * 4;
            const int4 v = yv[i];
            #pragma unroll
            for (int s = 0; s < 4; ++s) {
                const int yl = (s == 0) ? v.x : (s == 1) ? v.y : (s == 2) ? v.z : v.w;
                if (yl == myc) {
                    ++cnt;
                    const float4* xr = (const float4*)(xb + (size_t)(r0 + s) * D);
                    #pragma unroll
                    for (int j4 = 0; j4 < 4; ++j4) {
                        const float4 vv = xr[j4];
                        acc[j4*4+0] += vv.x; acc[j4*4+1] += vv.y;
                        acc[j4*4+2] += vv.z; acc[j4*4+3] += vv.w;
                    }
                }
            }
        }
    }

    #pragma unroll
    for (int off = 32; off; off >>= 1) {         // fixed order -> deterministic
        #pragma unroll
        for (int j = 0; j < 16; ++j) acc[j] += __shfl_xor(acc[j], off);
        cnt += __shfl_xor(cnt, off);
    }
    if (lane == 0) {
        #pragma unroll
        for (int j = 0; j < 16; ++j) red[wid][j] = acc[j];
        credw[wid] = cnt;
    }
    __syncthreads();
    if (tid < 16) {
        float tot = red[0][tid] + red[1][tid] + red[2][tid] + red[3][tid];
        float c = (float)(credw[0] + credw[1] + credw[2] + credw[3]);
        if (c < 0.5f) c = 1.f;           // class_counts + (counts < 0.01)
        tot /= c;
        const int k = kq8 * 16 + tid;
        pTg[((k >> 2) * 64 + (myc & 3) * 16 + (myc >> 2)) * 4 + (k & 3)] = tot;
    }
}

// ---- K_C: split-K 4x4-register-tile; 512 thr (2 waves/SIMD) ---------------
// waves 0-3: k4 in [0,16); waves 4-7: k4 in [16,32); same 64 rows.
__global__ __launch_bounds__(512) void kc_dist_loss(
    const float* __restrict__ x, const int* __restrict__ y,
    const float4* __restrict__ pTg4,    // [32][64] float4, finalized
    float* __restrict__ out)
{
    __shared__ float4 pT4[32 * 64];            // 32 KB, [k4][cc][cg]
    __shared__ float  comb[4][16][64];         // 16 KB upper-wave partials
    __shared__ float  wsum[4];
    const int tid = threadIdx.x;

    for (int o = tid; o < 32 * 64; o += 512) pT4[o] = pTg4[o];
    __syncthreads();

    const int lane = tid & 63;
    const int wid  = tid >> 6;           // 0..7
    const int wrow = wid & 3;            // row-wave id
    const int khal = wid >> 2;           // 0/1 -> k4 half
    const int k4lo = khal * 16;
    const int cg   = lane & 15;          // classes 4*cg + cc
    const int rg   = lane >> 4;          // row group within wave
    const int rbase = wrow * 16 + rg * 4;      // wave: 16 rows; thread: 4 rows
    const int row0 = M_HALF + blockIdx.x * KC_ROWS;

    const float4* xrow[4];
    #pragma unroll
    for (int r = 0; r < 4; ++r)
        xrow[r] = (const float4*)(x + (size_t)(row0 + rbase + r) * D);

    float acc[4][4];
    #pragma unroll
    for (int r = 0; r < 4; ++r)
        #pragma unroll
        for (int cc = 0; cc < 4; ++cc) acc[r][cc] = 0.f;

    float4 xv[4], xvn[4];
    #pragma unroll
    for (int r = 0; r < 4; ++r) xv[r] = xrow[r][k4lo];   // prologue

    #pragma unroll 4
    for (int k4i = 0; k4i < 16; ++k4i) {
        const int k4 = k4lo + k4i;
        if (k4i < 15) {
            #pragma unroll
            for (int r = 0; r < 4; ++r) xvn[r] = xrow[r][k4 + 1];  // prefetch
        }
        float4 pv[4];
        #pragma unroll
        for (int cc = 0; cc < 4; ++cc) pv[cc] = pT4[k4 * 64 + cc * 16 + cg];
        #pragma unroll
        for (int r = 0; r < 4; ++r) {
            #pragma unroll
            for (int cc = 0; cc < 4; ++cc) {
                float d;
                d = xv[r].x - pv[cc].x; acc[r][cc] = fmaf(d, fabsf(d), acc[r][cc]);
                d = xv[r].y - pv[cc].y; acc[r][cc] = fmaf(d, fabsf(d), acc[r][cc]);
                d = xv[r].z - pv[cc].z; acc[r][cc] = fmaf(d, fabsf(d), acc[r][cc]);
                d = xv[r].w - pv[cc].w; acc[r][cc] = fmaf(d, fabsf(d), acc[r][cc]);
            }
        }
        #pragma unroll
        for (int r = 0; r < 4; ++r) xv[r] = xvn[r];
    }

    // upper waves deposit partials (lane-major: conflict-free)
    if (khal == 1) {
        #pragma unroll
        for (int r = 0; r < 4; ++r)
            #pragma unroll
            for (int cc = 0; cc < 4; ++cc)
                comb[wrow][r * 4 + cc][lane] = acc[r][cc];
    }
    __syncthreads();

    if (khal == 0) {
        #pragma unroll
        for (int r = 0; r < 4; ++r)
            #pragma unroll
            for (int cc = 0; cc < 4; ++cc)
                acc[r][cc] += comb[wrow][r * 4 + cc][lane];

        const float ninv_d = -1.f / (float)D;
        float lsum = 0.f;
        #pragma unroll
        for (int r = 0; r < 4; ++r) {
            float dv0 = acc[r][0] * ninv_d, dv1 = acc[r][1] * ninv_d;
            float dv2 = acc[r][2] * ninv_d, dv3 = acc[r][3] * ninv_d;
            float mx = fmaxf(fmaxf(dv0, dv1), fmaxf(dv2, dv3));
            #pragma unroll
            for (int off = 8; off; off >>= 1) mx = fmaxf(mx, __shfl_xor(mx, off));
            float se = __expf(dv0 - mx) + __expf(dv1 - mx) +
                       __expf(dv2 - mx) + __expf(dv3 - mx);
            #pragma unroll
            for (int off = 8; off; off >>= 1) se += __shfl_xor(se, off);
            const float lse = mx + __logf(se);

            const int yt  = y[row0 + rbase + r];     // uniform within 16-lane group
            const int cct = yt & 3, cgt = yt >> 2;   // class c = 4*cg + cc
            const float v01 = (cct & 1) ? dv1 : dv0;
            const float v23 = (cct & 1) ? dv3 : dv2;
            const float val = (cct & 2) ? v23 : v01;
            const float dy  = __shfl(val, (lane & 48) | cgt);
            lsum += lse - dy;                        // -logp[y]
        }

        lsum += __shfl_xor(lsum, 16);                // sum 4 rg-groups
        lsum += __shfl_xor(lsum, 32);

        if (lane == 0) wsum[wrow] = lsum;
    }
    __syncthreads();
    if (tid == 0) {
        const float tot = (wsum[0] + wsum[1] + wsum[2] + wsum[3]) * (1.f / (float)M_HALF);
        atomicAdd(out, tot);
    }
}

extern "C" void kernel_launch(void* const* d_in, const int* in_sizes, int n_in,
                              void* d_out, int out_size, void* d_ws, size_t ws_size,
                              hipStream_t stream) {
    const float* x = (const float*)d_in[0];   // [32768][128]
    const int*   y = (const int*)d_in[1];     // [32768]
    float* out = (float*)d_out;

    float* pTg = (float*)d_ws;                // 8192 floats

    kp_proto<<<KP_BLOCKS, 256, 0, stream>>>(x, y, pTg, out);
    kc_dist_loss<<<KC_BLOCKS, 512, 0, stream>>>(x, y, (const float4*)pTg, out);
}

// Round 18
// 34.248 us; speedup vs baseline: 2.0473x; 1.0246x over previous
//
#include <hip/hip_runtime.h>

#define M_HALF 16384
#define D 128
#define C 64

#define KP_BLOCKS 512            // block = (kq8 = blk>>6 in 0..7, class = blk&63)
#define KC_BLOCKS 512
#define KC_ROWS 32

// ---- K_P: direct prototype build (r15, verbatim — validated) --------------
__global__ __launch_bounds__(256) void kp_proto(
    const float* __restrict__ x, const int* __restrict__ y,
    float* __restrict__ pTg,     // float idx: (k4*64 + cc*16 + cg)*4 + j
    float* __restrict__ out)
{
    __shared__ float red[4][16];
    __shared__ int   credw[4];
    const int tid  = threadIdx.x;
    const int lane = tid & 63;
    const int wid  = tid >> 6;
    const int blk  = blockIdx.x;
    const int myc  = blk & 63;
    const int kq8  = blk >> 6;           // 0..7 -> 16-float slice

    if (blk == 0 && tid == 0) out[0] = 0.f;   // before K_C's atomicAdd

    float acc[16];
    #pragma unroll
    for (int j = 0; j < 16; ++j) acc[j] = 0.f;
    int cnt = 0;

    const float* xb = x + kq8 * 16;
    const int4* y4 = (const int4*)y;

    #pragma unroll
    for (int half = 0; half < 2; ++half) {
        int4 yv[8];
        #pragma unroll
        for (int i = 0; i < 8; ++i)                  // 8 independent int4 loads
            yv[i] = y4[(half * 8 + i) * 256 + tid];  // coalesced across threads
        #pragma unroll
        for (int i = 0; i < 8; ++i) {
            const int r0 = ((half * 8 + i) * 256 + tid) * 4;
            const int4 v = yv[i];
            #pragma unroll
            for (int s = 0; s < 4; ++s) {
                const int yl = (s == 0) ? v.x : (s == 1) ? v.y : (s == 2) ? v.z : v.w;
                if (yl == myc) {
                    ++cnt;
                    const float4* xr = (const float4*)(xb + (size_t)(r0 + s) * D);
                    #pragma unroll
                    for (int j4 = 0; j4 < 4; ++j4) {
                        const float4 vv = xr[j4];
                        acc[j4*4+0] += vv.x; acc[j4*4+1] += vv.y;
                        acc[j4*4+2] += vv.z; acc[j4*4+3] += vv.w;
                    }
                }
            }
        }
    }

    #pragma unroll
    for (int off = 32; off; off >>= 1) {         // fixed order -> deterministic
        #pragma unroll
        for (int j = 0; j < 16; ++j) acc[j] += __shfl_xor(acc[j], off);
        cnt += __shfl_xor(cnt, off);
    }
    if (lane == 0) {
        #pragma unroll
        for (int j = 0; j < 16; ++j) red[wid][j] = acc[j];
        credw[wid] = cnt;
    }
    __syncthreads();
    if (tid < 16) {
        float tot = red[0][tid] + red[1][tid] + red[2][tid] + red[3][tid];
        float c = (float)(credw[0] + credw[1] + credw[2] + credw[3]);
        if (c < 0.5f) c = 1.f;           // class_counts + (counts < 0.01)
        tot /= c;
        const int k = kq8 * 16 + tid;
        pTg[((k >> 2) * 64 + (myc & 3) * 16 + (myc >> 2)) * 4 + (k & 3)] = tot;
    }
}

// ---- K_C: split-K 2x4-register-tile; 512 thr, 2 blocks/CU = 4 waves/SIMD --
// waves 0-3: k4 in [0,16); waves 4-7: k4 in [16,32); same 32 rows.
__global__ __launch_bounds__(512) void kc_dist_loss(
    const float* __restrict__ x, const int* __restrict__ y,
    const float4* __restrict__ pTg4,    // [32][64] float4, finalized
    float* __restrict__ out)
{
    __shared__ float4 pT4[32 * 64];            // 32 KB, [k4][cc][cg]
    __shared__ float  comb[4][8][64];          // 8 KB upper-wave partials
    __shared__ float  wsum[4];
    const int tid = threadIdx.x;

    for (int o = tid; o < 32 * 64; o += 512) pT4[o] = pTg4[o];
    __syncthreads();

    const int lane = tid & 63;
    const int wid  = tid >> 6;           // 0..7
    const int wrow = wid & 3;            // row-wave id
    const int khal = wid >> 2;           // 0/1 -> k4 half
    const int k4lo = khal * 16;
    const int cg   = lane & 15;          // classes 4*cg + cc
    const int rg   = lane >> 4;          // row group within wave
    const int rbase = wrow * 8 + rg * 2;       // wave: 8 rows; thread: 2 rows
    const int row0 = M_HALF + blockIdx.x * KC_ROWS;

    const float4* xrow[2];
    #pragma unroll
    for (int r = 0; r < 2; ++r)
        xrow[r] = (const float4*)(x + (size_t)(row0 + rbase + r) * D);

    float acc[2][4];
    #pragma unroll
    for (int r = 0; r < 2; ++r)
        #pragma unroll
        for (int cc = 0; cc < 4; ++cc) acc[r][cc] = 0.f;

    float4 xv[2], xvn[2];
    #pragma unroll
    for (int r = 0; r < 2; ++r) xv[r] = xrow[r][k4lo];   // prologue

    #pragma unroll 4
    for (int k4i = 0; k4i < 16; ++k4i) {
        const int k4 = k4lo + k4i;
        if (k4i < 15) {
            #pragma unroll
            for (int r = 0; r < 2; ++r) xvn[r] = xrow[r][k4 + 1];  // prefetch
        }
        float4 pv[4];
        #pragma unroll
        for (int cc = 0; cc < 4; ++cc) pv[cc] = pT4[k4 * 64 + cc * 16 + cg];
        #pragma unroll
        for (int r = 0; r < 2; ++r) {
            #pragma unroll
            for (int cc = 0; cc < 4; ++cc) {
                float d;
                d = xv[r].x - pv[cc].x; acc[r][cc] = fmaf(d, fabsf(d), acc[r][cc]);
                d = xv[r].y - pv[cc].y; acc[r][cc] = fmaf(d, fabsf(d), acc[r][cc]);
                d = xv[r].z - pv[cc].z; acc[r][cc] = fmaf(d, fabsf(d), acc[r][cc]);
                d = xv[r].w - pv[cc].w; acc[r][cc] = fmaf(d, fabsf(d), acc[r][cc]);
            }
        }
        #pragma unroll
        for (int r = 0; r < 2; ++r) xv[r] = xvn[r];
    }

    // upper waves deposit partials (lane-major: conflict-free)
    if (khal == 1) {
        #pragma unroll
        for (int r = 0; r < 2; ++r)
            #pragma unroll
            for (int cc = 0; cc < 4; ++cc)
                comb[wrow][r * 4 + cc][lane] = acc[r][cc];
    }
    __syncthreads();

    if (khal == 0) {
        #pragma unroll
        for (int r = 0; r < 2; ++r)
            #pragma unroll
            for (int cc = 0; cc < 4; ++cc)
                acc[r][cc] += comb[wrow][r * 4 + cc][lane];

        const float ninv_d = -1.f / (float)D;
        float lsum = 0.f;
        #pragma unroll
        for (int r = 0; r < 2; ++r) {
            float dv0 = acc[r][0] * ninv_d, dv1 = acc[r][1] * ninv_d;
            float dv2 = acc[r][2] * ninv_d, dv3 = acc[r][3] * ninv_d;
            float mx = fmaxf(fmaxf(dv0, dv1), fmaxf(dv2, dv3));
            #pragma unroll
            for (int off = 8; off; off >>= 1) mx = fmaxf(mx, __shfl_xor(mx, off));
            float se = __expf(dv0 - mx) + __expf(dv1 - mx) +
                       __expf(dv2 - mx) + __expf(dv3 - mx);
            #pragma unroll
            for (int off = 8; off; off >>= 1) se += __shfl_xor(se, off);
            const float lse = mx + __logf(se);

            const int yt  = y[row0 + rbase + r];     // uniform within 16-lane group
            const int cct = yt & 3, cgt = yt >> 2;   // class c = 4*cg + cc
            const float v01 = (cct & 1) ? dv1 : dv0;
            const float v23 = (cct & 1) ? dv3 : dv2;
            const float val = (cct & 2) ? v23 : v01;
            const float dy  = __shfl(val, (lane & 48) | cgt);
            lsum += lse - dy;                        // -logp[y]
        }

        lsum += __shfl_xor(lsum, 16);                // sum 4 rg-groups
        lsum += __shfl_xor(lsum, 32);

        if (lane == 0) wsum[wrow] = lsum;
    }
    __syncthreads();
    if (tid == 0) {
        const float tot = (wsum[0] + wsum[1] + wsum[2] + wsum[3]) * (1.f / (float)M_HALF);
        atomicAdd(out, tot);
    }
}

extern "C" void kernel_launch(void* const* d_in, const int* in_sizes, int n_in,
                              void* d_out, int out_size, void* d_ws, size_t ws_size,
                              hipStream_t stream) {
    const float* x = (const float*)d_in[0];   // [32768][128]
    const int*   y = (const int*)d_in[1];     // [32768]
    float* out = (float*)d_out;

    float* pTg = (float*)d_ws;                // 8192 floats

    kp_proto<<<KP_BLOCKS, 256, 0, stream>>>(x, y, pTg, out);
    kc_dist_loss<<<KC_BLOCKS, 512, 0, stream>>>(x, y, (const float4*)pTg, out);
}

// Round 19
// 30.544 us; speedup vs baseline: 2.2956x; 1.1213x over previous
//
#include <hip/hip_runtime.h>

#define M_HALF 16384
#define D 128
#define C 64

#define KP_BLOCKS 512            // block = (kq8 = blk>>6 in 0..7, class = blk&63)
#define KC_BLOCKS 512
#define KC_ROWS 32
#define LCAP 1536                // row-list capacity (fixed-key counts ~256)

// ---- K_P: compact-then-gather prototype build -----------------------------
// Phase 1: scan y, compact matching row indices into LDS list.
// Phase 2: full-lane cooperative gather (16-lane group per row, 64B segments).
__global__ __launch_bounds__(256) void kp_proto(
    const float* __restrict__ x, const int* __restrict__ y,
    float* __restrict__ pTg,     // float idx: (k4*64 + cc*16 + cg)*4 + j
    float* __restrict__ out)
{
    __shared__ int   list[LCAP];
    __shared__ int   nm;
    __shared__ float red[4][16];
    const int tid  = threadIdx.x;
    const int lane = tid & 63;
    const int wid  = tid >> 6;
    const int blk  = blockIdx.x;
    const int myc  = blk & 63;
    const int kq8  = blk >> 6;           // 0..7 -> 16-float slice

    if (tid == 0) nm = 0;
    if (blk == 0 && tid == 0) out[0] = 0.f;   // before K_C's atomicAdd
    __syncthreads();

    // scan: 16 int4 per thread, coalesced; wave-coalesced LDS atomics (m20)
    const int4* y4 = (const int4*)y;
    #pragma unroll 4
    for (int i = 0; i < 16; ++i) {
        const int4 v = y4[i * 256 + tid];
        const int r0 = (i * 256 + tid) * 4;
        if (v.x == myc) { int p = atomicAdd(&nm, 1); if (p < LCAP) list[p] = r0;     }
        if (v.y == myc) { int p = atomicAdd(&nm, 1); if (p < LCAP) list[p] = r0 + 1; }
        if (v.z == myc) { int p = atomicAdd(&nm, 1); if (p < LCAP) list[p] = r0 + 2; }
        if (v.w == myc) { int p = atomicAdd(&nm, 1); if (p < LCAP) list[p] = r0 + 3; }
    }
    __syncthreads();
    const int n  = nm;
    const int nl = (n < LCAP) ? n : LCAP;

    // gather: 16 groups of 16 lanes; group g reads row list[i]'s 64B slice
    const int grp = tid >> 4;            // 0..15
    const int fid = tid & 15;            // float within slice
    const float* xb = x + kq8 * 16 + fid;
    float acc = 0.f;
    #pragma unroll 2
    for (int i = grp; i < nl; i += 16)
        acc += xb[(size_t)list[i] * D];  // 4B loads, 64B segments, independent

    // reduce groups sharing fid: xor 16/32 within wave, then cross-wave LDS
    acc += __shfl_xor(acc, 16);
    acc += __shfl_xor(acc, 32);
    if (lane < 16) red[wid][lane] = acc;
    __syncthreads();
    if (tid < 16) {
        float tot = red[0][tid] + red[1][tid] + red[2][tid] + red[3][tid];
        float c = (float)n;
        if (c < 0.5f) c = 1.f;           // class_counts + (counts < 0.01)
        tot /= c;
        const int k = kq8 * 16 + tid;
        pTg[((k >> 2) * 64 + (myc & 3) * 16 + (myc >> 2)) * 4 + (k & 3)] = tot;
    }
}

// ---- K_C: split-K 2x4-register-tile; 512 thr, 2 blocks/CU = 4 waves/SIMD --
// waves 0-3: k4 in [0,16); waves 4-7: k4 in [16,32); same 32 rows.
__global__ __launch_bounds__(512) void kc_dist_loss(
    const float* __restrict__ x, const int* __restrict__ y,
    const float4* __restrict__ pTg4,    // [32][64] float4, finalized
    float* __restrict__ out)
{
    __shared__ float4 pT4[32 * 64];            // 32 KB, [k4][cc][cg]
    __shared__ float  comb[4][8][64];          // 8 KB upper-wave partials
    __shared__ float  wsum[4];
    const int tid = threadIdx.x;

    for (int o = tid; o < 32 * 64; o += 512) pT4[o] = pTg4[o];
    __syncthreads();

    const int lane = tid & 63;
    const int wid  = tid >> 6;           // 0..7
    const int wrow = wid & 3;            // row-wave id
    const int khal = wid >> 2;           // 0/1 -> k4 half
    const int k4lo = khal * 16;
    const int cg   = lane & 15;          // classes 4*cg + cc
    const int rg   = lane >> 4;          // row group within wave
    const int rbase = wrow * 8 + rg * 2;       // wave: 8 rows; thread: 2 rows
    const int row0 = M_HALF + blockIdx.x * KC_ROWS;

    const float4* xrow[2];
    #pragma unroll
    for (int r = 0; r < 2; ++r)
        xrow[r] = (const float4*)(x + (size_t)(row0 + rbase + r) * D);

    float acc[2][4];
    #pragma unroll
    for (int r = 0; r < 2; ++r)
        #pragma unroll
        for (int cc = 0; cc < 4; ++cc) acc[r][cc] = 0.f;

    float4 xv[2], xvn[2];
    #pragma unroll
    for (int r = 0; r < 2; ++r) xv[r] = xrow[r][k4lo];   // prologue

    #pragma unroll 4
    for (int k4i = 0; k4i < 16; ++k4i) {
        const int k4 = k4lo + k4i;
        if (k4i < 15) {
            #pragma unroll
            for (int r = 0; r < 2; ++r) xvn[r] = xrow[r][k4 + 1];  // prefetch
        }
        float4 pv[4];
        #pragma unroll
        for (int cc = 0; cc < 4; ++cc) pv[cc] = pT4[k4 * 64 + cc * 16 + cg];
        #pragma unroll
        for (int r = 0; r < 2; ++r) {
            #pragma unroll
            for (int cc = 0; cc < 4; ++cc) {
                float d;
                d = xv[r].x - pv[cc].x; acc[r][cc] = fmaf(d, fabsf(d), acc[r][cc]);
                d = xv[r].y - pv[cc].y; acc[r][cc] = fmaf(d, fabsf(d), acc[r][cc]);
                d = xv[r].z - pv[cc].z; acc[r][cc] = fmaf(d, fabsf(d), acc[r][cc]);
                d = xv[r].w - pv[cc].w; acc[r][cc] = fmaf(d, fabsf(d), acc[r][cc]);
            }
        }
        #pragma unroll
        for (int r = 0; r < 2; ++r) xv[r] = xvn[r];
    }

    // upper waves deposit partials (lane-major: conflict-free)
    if (khal == 1) {
        #pragma unroll
        for (int r = 0; r < 2; ++r)
            #pragma unroll
            for (int cc = 0; cc < 4; ++cc)
                comb[wrow][r * 4 + cc][lane] = acc[r][cc];
    }
    __syncthreads();

    if (khal == 0) {
        #pragma unroll
        for (int r = 0; r < 2; ++r)
            #pragma unroll
            for (int cc = 0; cc < 4; ++cc)
                acc[r][cc] += comb[wrow][r * 4 + cc][lane];

        const float ninv_d = -1.f / (float)D;
        float lsum = 0.f;
        #pragma unroll
        for (int r = 0; r < 2; ++r) {
            float dv0 = acc[r][0] * ninv_d, dv1 = acc[r][1] * ninv_d;
            float dv2 = acc[r][2] * ninv_d, dv3 = acc[r][3] * ninv_d;
            float mx = fmaxf(fmaxf(dv0, dv1), fmaxf(dv2, dv3));
            #pragma unroll
            for (int off = 8; off; off >>= 1) mx = fmaxf(mx, __shfl_xor(mx, off));
            float se = __expf(dv0 - mx) + __expf(dv1 - mx) +
                       __expf(dv2 - mx) + __expf(dv3 - mx);
            #pragma unroll
            for (int off = 8; off; off >>= 1) se += __shfl_xor(se, off);
            const float lse = mx + __logf(se);

            const int yt  = y[row0 + rbase + r];     // uniform within 16-lane group
            const int cct = yt & 3, cgt = yt >> 2;   // class c = 4*cg + cc
            const float v01 = (cct & 1) ? dv1 : dv0;
            const float v23 = (cct & 1) ? dv3 : dv2;
            const float val = (cct & 2) ? v23 : v01;
            const float dy  = __shfl(val, (lane & 48) | cgt);
            lsum += lse - dy;                        // -logp[y]
        }

        lsum += __shfl_xor(lsum, 16);                // sum 4 rg-groups
        lsum += __shfl_xor(lsum, 32);

        if (lane == 0) wsum[wrow] = lsum;
    }
    __syncthreads();
    if (tid == 0) {
        const float tot = (wsum[0] + wsum[1] + wsum[2] + wsum[3]) * (1.f / (float)M_HALF);
        atomicAdd(out, tot);
    }
}

extern "C" void kernel_launch(void* const* d_in, const int* in_sizes, int n_in,
                              void* d_out, int out_size, void* d_ws, size_t ws_size,
                              hipStream_t stream) {
    const float* x = (const float*)d_in[0];   // [32768][128]
    const int*   y = (const int*)d_in[1];     // [32768]
    float* out = (float*)d_out;

    float* pTg = (float*)d_ws;                // 8192 floats

    kp_proto<<<KP_BLOCKS, 256, 0, stream>>>(x, y, pTg, out);
    kc_dist_loss<<<KC_BLOCKS, 512, 0, stream>>>(x, y, (const float4*)pTg, out);
}